// Round 12
// baseline (39.051 us; speedup 1.0000x reference)
//
#include <hip/hip_runtime.h>
#include <math.h>

#define BATCH 32
#define CH 3
#define HH 256
#define WW 256
#define PP 32
#define NPATCH 4

typedef __attribute__((ext_vector_type(8))) short short8;
typedef __attribute__((ext_vector_type(4))) float f32x4;

__device__ __forceinline__ unsigned short f2bf(float f) {
  union { float f; unsigned u; } cv;
  cv.f = f;
  unsigned u = cv.u;
  u += 0x7FFFu + ((u >> 16) & 1u);
  return (unsigned short)(u >> 16);
}

__device__ __forceinline__ unsigned cvt_pk_bf16(float lo, float hi) {
  unsigned r;
  asm("v_cvt_pk_bf16_f32 %0, %1, %2" : "=v"(r) : "v"(lo), "v"(hi));
  return r;
}

// c1 layout permutation: short-col q of the h1 buffer holds channel c1perm(q)
__device__ __host__ __forceinline__ int c1perm(int q) {
  return (q & 1) ? 16 + (q >> 1) : (q >> 1);
}

// ================= K1: fused copy + band-pool (+ weight pack) =================
__global__ __launch_bounds__(256) void prep_kernel(
    const float* __restrict__ x, float* __restrict__ out,
    float* __restrict__ feat, const float* __restrict__ w1,
    const float* __restrict__ w2, const float* __restrict__ w3,
    const float* __restrict__ pw1, unsigned short* __restrict__ w1f,
    unsigned short* __restrict__ w2f, unsigned short* __restrict__ w3f,
    float* __restrict__ pw1t) {
  const int blk = blockIdx.x;
  const int t = threadIdx.x;

  if (blk >= 792) {
    const int seg = blk - 792;
#pragma unroll
    for (int q = 0; q < 4; ++q) {
      int idx = seg * 1024 + q * 256 + t;  // 0..8191
      if (idx < 1024) {
        int nt = idx >> 9, lane_ = (idx >> 3) & 63, j = idx & 7;
        int lrow_ = lane_ & 15, lgrp_ = lane_ >> 4;
        int k = lgrp_ * 8 + j;
        w1f[idx] = f2bf(k < 27 ? w1[(nt * 16 + lrow_) * 27 + k] : 0.f);
      } else if (idx < 5632) {
        int id2 = idx - 1024;
        int tap = id2 >> 9, lane_ = (id2 >> 3) & 63, j = id2 & 7;
        int lrow_ = lane_ & 15, lgrp_ = lane_ >> 4;
        int c1p = c1perm(lgrp_ * 8 + j);
        w2f[id2] = f2bf(w2[lrow_ * 288 + c1p * 9 + tap]);
      } else if (idx < 8192) {
        int id3 = idx - 5632;
        int kk = id3 >> 9, lane_ = (id3 >> 3) & 63, j = id3 & 7;
        int lrow_ = lane_ & 15, lgrp_ = lane_ >> 4;
        int tap = 2 * kk + (lgrp_ >> 1);
        int c2 = (lgrp_ & 1) * 8 + j;
        float v = (lrow_ < 3 && tap < 9) ? w3[lrow_ * 144 + c2 * 9 + tap] : 0.f;
        w3f[id3] = f2bf(v);
      }
    }
    return;
  }

  if (blk >= 768) {
    // pw1 transpose: pw1[128][192] -> pw1t[192][128]; 24 tiles of 32x32
    const int tile = blk - 768;
    const int ko = (tile % 6) * 32;
    const int to = (tile / 6) * 32;
    __shared__ float tl[32][33];
    int ty = t >> 5, tx = t & 31;
#pragma unroll
    for (int r = 0; r < 4; ++r) {
      int row = r * 8 + ty;
      tl[row][tx] = pw1[(to + row) * 192 + ko + tx];
    }
    __syncthreads();
#pragma unroll
    for (int r = 0; r < 4; ++r) {
      int row = r * 8 + ty;
      pw1t[(ko + row) * 128 + to + tx] = tl[tx][row];
    }
    return;
  }

  // band block (b,c,i): copy 32x256 rows + full pool reduce in-block
  const int b = blk / 24;
  const int rem = blk - b * 24;
  const int c = rem >> 3;
  const int i = rem & 7;
  const int wv = t >> 6;
  const int lane = t & 63;
  const int j = lane >> 3;

  __shared__ float part[32];

  const size_t base4 = ((size_t)((b * 3 + c) * 256 + i * 32)) * 64;
  float s = 0.f;
#pragma unroll
  for (int k = 0; k < 8; ++k) {
    int r = k * 4 + wv;
    size_t F = base4 + (size_t)r * 64 + lane;
    float4 v = ((const float4*)x)[F];
    ((float4*)out)[F] = v;
    s += v.x + v.y + v.z + v.w;
  }
  s += __shfl_xor(s, 1, 64);
  s += __shfl_xor(s, 2, 64);
  s += __shfl_xor(s, 4, 64);
  if ((lane & 7) == 0) part[wv * 8 + j] = s;
  __syncthreads();
  if (t < 8) {
    float tot = part[t] + part[8 + t] + part[16 + t] + part[24 + t];
    feat[b * 192 + c * 64 + i * 8 + t] = tot * (1.f / 1024.f);
  }
}

// ================= K2: MLP -> posw (one block per batch image) ===============
__global__ __launch_bounds__(256) void mlp_kernel(
    const float* __restrict__ feat, const float* __restrict__ pw1t,
    const float* __restrict__ pb1, const float* __restrict__ pw2,
    const float* __restrict__ pb2, int* __restrict__ posw) {
  const int b = blockIdx.x;
  const int t = threadIdx.x;
  __shared__ float fs[192];
  __shared__ float part[2][128];
  __shared__ float hs[128];

  if (t < 192) fs[t] = feat[b * 192 + t];
  __syncthreads();

  {
    const int u = t & 127, h = t >> 7;
    float a0 = 0.f, a1 = 0.f;
    const float* wp = pw1t + (h * 96) * 128 + u;
    const float* fp = fs + h * 96;
#pragma unroll 12
    for (int k = 0; k < 96; k += 2) {
      a0 = fmaf(fp[k], wp[k * 128], a0);
      a1 = fmaf(fp[k + 1], wp[(k + 1) * 128], a1);
    }
    part[h][u] = a0 + a1;
  }
  __syncthreads();
  if (t < 128) hs[t] = fmaxf(part[0][t] + part[1][t] + pb1[t], 0.f);
  __syncthreads();

  const int wv = t >> 6, hl = (t >> 5) & 1, l = t & 31;
  const int jj = wv * 2 + hl;
  float a = 0.f;
#pragma unroll
  for (int q = 0; q < 4; ++q)
    a = fmaf(hs[q * 32 + l], pw2[jj * 128 + q * 32 + l], a);
#pragma unroll
  for (int m = 1; m <= 16; m <<= 1) a += __shfl_xor(a, m, 32);
  if (l == 0) {
    float a2 = a + pb2[jj];
    float sgm = 1.f / (1.f + expf(-a2));
    posw[b * 8 + jj] = (int)floorf(sgm * (float)(HH - PP));
  }
}

// ================= K3: MFMA patch pipeline (8-row blocks, 512 thr) ===========
// frames: out 8x32 @ (y0+rb, x0); h2 10x34 @ (-1,-1); h1/xcol 12x36 @ (-2,-2);
//         x 14x38 @ (-3,-3)
__global__ __launch_bounds__(512, 4) void patch_kernel(
    const float* __restrict__ x, float* __restrict__ out,
    const float* __restrict__ b1, const float* __restrict__ b2,
    const float* __restrict__ b3, const int* __restrict__ posw,
    const unsigned short* __restrict__ w1f, const unsigned short* __restrict__ w2f,
    const unsigned short* __restrict__ w3f) {
  const int blk = blockIdx.x;
  const int s = blk & 3;
  const int p = (blk >> 2) & 3;
  const int b = blk >> 4;
  const int rb = s * 8;
  const int t = threadIdx.x;
  const int wv = t >> 6;
  const int lane = t & 63;
  const int lrow = lane & 15;   // MFMA A-row / B-col / D-col
  const int lgrp = lane >> 4;   // MFMA k-group; D-row = lgrp*4+reg

  __shared__ __align__(16) float xs[3][532];               // 6384 B
  __shared__ __align__(16) unsigned short xcol[432 * 36];  // 31104 B
  __shared__ __align__(16) unsigned short h1b[432 * 36];   // 31104 B (c1-interleaved)
  __shared__ __align__(16) unsigned short h2ls[352 * 16];  // 11264 B
  // total 79856 B -> 2 blocks/CU

  const int y0 = posw[b * 8 + p * 2 + 0];
  const int x0 = posw[b * 8 + p * 2 + 1];

  // ---- stage x window immediately (zero-padded f32)
#pragma unroll
  for (int k = 0; k < 4; ++k) {
    int idx = t + 512 * k;
    if (idx < 1596) {
      int c = idx / 532;
      int r = idx - c * 532;
      int ky = r / 38, kx = r - (r / 38) * 38;
      int gy = y0 + rb - 3 + ky, gx = x0 - 3 + kx;
      float v = 0.f;
      if ((unsigned)gy < 256u && (unsigned)gx < 256u)
        v = x[((size_t)(b * 3 + c) * 256 + gy) * 256 + gx];
      xs[c][r] = v;
    }
  }

  // fragment loads (overlap with stage latency)
  short8 b1f[2], b2f[9], b3f[5];
#pragma unroll
  for (int nt = 0; nt < 2; ++nt)
    b1f[nt] = *(const short8*)&w1f[(nt * 64 + lane) * 8];
#pragma unroll
  for (int tap = 0; tap < 9; ++tap)
    b2f[tap] = *(const short8*)&w2f[(tap * 64 + lane) * 8];
#pragma unroll
  for (int kk = 0; kk < 5; ++kk)
    b3f[kk] = *(const short8*)&w3f[(kk * 64 + lane) * 8];
  float b1v0 = b1[lrow], b1v1 = b1[16 + lrow];
  float bias2 = b2[lrow];
  float bias3 = (lrow < 3) ? b3[lrow] : 0.f;

  __syncthreads();

  // ---- im2col of xs -> xcol (row=pos, k=c*9+dy*3+dx, 27 pad 32); 432 positions
  if (t < 432) {
    int pos = t;
    int jy = pos / 36, jx = pos - (pos / 36) * 36;
    unsigned short cv[32];
#pragma unroll
    for (int c = 0; c < 3; ++c)
#pragma unroll
      for (int dy = 0; dy < 3; ++dy)
#pragma unroll
        for (int dx = 0; dx < 3; ++dx)
          cv[c * 9 + dy * 3 + dx] = f2bf(xs[c][(jy + dy) * 38 + (jx + dx)]);
#pragma unroll
    for (int k = 27; k < 32; ++k) cv[k] = 0;
#pragma unroll
    for (int qq = 0; qq < 4; ++qq) {
      short8 v8;
#pragma unroll
      for (int j = 0; j < 8; ++j) v8[j] = (short)cv[qq * 8 + j];
      *(short8*)&xcol[pos * 36 + qq * 8] = v8;
    }
  }
  __syncthreads();

  // ---- h1 GEMM  M=432 (27 tiles), N=32, K=32; epilogue into h1b (no barrier
  //      needed between MFMA-reads(xcol) and epi-writes(h1b): disjoint buffers)
  f32x4 acc1[4][2];
#pragma unroll
  for (int i = 0; i < 4; ++i) {
    int mt = wv + 8 * i;
    if (mt < 27) {
      short8 a = *(const short8*)&xcol[(mt * 16 + lrow) * 36 + lgrp * 8];
      f32x4 z = f32x4{0.f, 0.f, 0.f, 0.f};
#pragma unroll
      for (int nt = 0; nt < 2; ++nt)
        acc1[i][nt] = __builtin_amdgcn_mfma_f32_16x16x32_bf16(a, b1f[nt], z, 0, 0, 0);
    }
  }
  // epilogue: bias+relu+mask -> h1b[pos][2*lrow..+1] packed u32 (c1-interleaved)
#pragma unroll
  for (int i = 0; i < 4; ++i) {
    int mt = wv + 8 * i;
    if (mt < 27) {
#pragma unroll
      for (int r = 0; r < 4; ++r) {
        int pos = mt * 16 + lgrp * 4 + r;
        int jy = pos / 36, jx = pos - (pos / 36) * 36;
        bool inim = ((unsigned)(y0 + rb - 2 + jy) < 256u) &&
                    ((unsigned)(x0 - 2 + jx) < 256u);
        float v0 = inim ? fmaxf(acc1[i][0][r] + b1v0, 0.f) : 0.f;
        float v1 = inim ? fmaxf(acc1[i][1][r] + b1v1, 0.f) : 0.f;
        *(unsigned*)&h1b[pos * 36 + 2 * lrow] = cvt_pk_bf16(v0, v1);
      }
    }
  }
  __syncthreads();

  // ---- h2 GEMM, M=352 (22 tiles, 340 valid), K = 9 taps x 32 c1 (perm order)
  f32x4 acc[3];
#pragma unroll
  for (int i = 0; i < 3; ++i) {
    int mt = wv + 8 * i;
    if (mt < 22) {
      int pos = mt * 16 + lrow;
      int posc = pos < 340 ? pos : 339;
      int iy = posc / 34, ix = posc - (posc / 34) * 34;
      const unsigned short* abase = &h1b[(iy * 36 + ix) * 36 + lgrp * 8];
      f32x4 c = f32x4{0.f, 0.f, 0.f, 0.f};
#pragma unroll
      for (int dy = 0; dy < 3; ++dy)
#pragma unroll
        for (int dx = 0; dx < 3; ++dx) {
          short8 a = *(const short8*)(abase + (dy * 36 + dx) * 36);
          c = __builtin_amdgcn_mfma_f32_16x16x32_bf16(a, b2f[dy * 3 + dx], c, 0, 0, 0);
        }
      acc[i] = c;
    } else {
      acc[i] = f32x4{0.f, 0.f, 0.f, 0.f};
    }
  }
#pragma unroll
  for (int i = 0; i < 3; ++i) {
    int mt = wv + 8 * i;
    if (mt < 22) {
#pragma unroll
      for (int r = 0; r < 4; ++r) {
        int pos = mt * 16 + lgrp * 4 + r;
        if (pos < 340) {
          int iy = pos / 34, ix = pos - (pos / 34) * 34;
          bool inim = ((unsigned)(y0 + rb - 1 + iy) < 256u) &&
                      ((unsigned)(x0 - 1 + ix) < 256u);
          float v = fmaxf(acc[i][r] + bias2, 0.f);
          h2ls[pos * 16 + lrow] = inim ? f2bf(v) : (unsigned short)0;
        }
      }
    }
  }
  __syncthreads();

  // ---- h3 GEMM, M=256 (16 tiles), K=144 pad 160
  f32x4 acc3[2];
#pragma unroll
  for (int i = 0; i < 2; ++i) {
    int mt = wv * 2 + i;
    int pix = mt * 16 + lrow;
    int oy = pix >> 5, ox = pix & 31;
    f32x4 c = f32x4{0.f, 0.f, 0.f, 0.f};
#pragma unroll
    for (int kk = 0; kk < 5; ++kk) {
      int tap = 2 * kk + (lgrp >> 1);
      short8 a = short8{0, 0, 0, 0, 0, 0, 0, 0};
      if (tap < 9) {
        int dy = (tap * 11) >> 5;
        int dx = tap - dy * 3;
        a = *(const short8*)&h2ls[((oy + dy) * 34 + (ox + dx)) * 16 + (lgrp & 1) * 8];
      }
      c = __builtin_amdgcn_mfma_f32_16x16x32_bf16(a, b3f[kk], c, 0, 0, 0);
    }
    acc3[i] = c;
  }
  if (lrow < 3) {
#pragma unroll
    for (int i = 0; i < 2; ++i) {
      int mt = wv * 2 + i;
#pragma unroll
      for (int r = 0; r < 4; ++r) {
        int pix = mt * 16 + lgrp * 4 + r;
        int oy = pix >> 5, ox = pix & 31;
        float v = acc3[i][r] + bias3;
        float e = __expf(2.f * v);
        float val = (1.f - 2.f / (e + 1.f)) * 0.1f;
        atomicAdd(&out[((size_t)(b * 3 + lrow) * 256 + (y0 + rb + oy)) * 256 +
                       (x0 + ox)],
                  val);
      }
    }
  }
}

extern "C" void kernel_launch(void* const* d_in, const int* in_sizes, int n_in,
                              void* d_out, int out_size, void* d_ws, size_t ws_size,
                              hipStream_t stream) {
  const float* x   = (const float*)d_in[0];
  const float* w1  = (const float*)d_in[1];
  const float* b1  = (const float*)d_in[2];
  const float* w2  = (const float*)d_in[3];
  const float* b2  = (const float*)d_in[4];
  const float* w3  = (const float*)d_in[5];
  const float* b3  = (const float*)d_in[6];
  const float* pw1 = (const float*)d_in[7];
  const float* pb1 = (const float*)d_in[8];
  const float* pw2 = (const float*)d_in[9];
  const float* pb2 = (const float*)d_in[10];
  float* out = (float*)d_out;

  // ws layout (total ~136 KB)
  float* feat = (float*)d_ws;                                    // 6144 f  @0
  int* posw = (int*)((char*)d_ws + 24576 - 2048);                // 256 ints
  unsigned short* w1f = (unsigned short*)((char*)d_ws + 24576);  // 1024 us
  unsigned short* w2f = (unsigned short*)((char*)d_ws + 26624);  // 4608 us
  unsigned short* w3f = (unsigned short*)((char*)d_ws + 35840);  // 2560 us
  float* pw1t = (float*)((char*)d_ws + 40960);                   // 24576 f

  prep_kernel<<<800, 256, 0, stream>>>(x, out, feat, w1, w2, w3, pw1,
                                       w1f, w2f, w3f, pw1t);
  mlp_kernel<<<BATCH, 256, 0, stream>>>(feat, pw1t, pb1, pw2, pb2, posw);
  patch_kernel<<<BATCH * NPATCH * 4, 512, 0, stream>>>(
      x, out, b1, b2, b3, posw, w1f, w2f, w3f);
}

// Round 14
// 31.281 us; speedup vs baseline: 1.2484x; 1.2484x over previous
//
#include <hip/hip_runtime.h>
#include <math.h>

#define BATCH 32
#define CH 3
#define HH 256
#define WW 256
#define PP 32
#define NPATCH 4

typedef __attribute__((ext_vector_type(8))) short short8;
typedef __attribute__((ext_vector_type(4))) float f32x4;

__device__ __forceinline__ unsigned short f2bf(float f) {
  union { float f; unsigned u; } cv;
  cv.f = f;
  unsigned u = cv.u;
  u += 0x7FFFu + ((u >> 16) & 1u);
  return (unsigned short)(u >> 16);
}

// ================= K1: fused copy + band-pool (+ weight pack) =================
__global__ __launch_bounds__(256) void prep_kernel(
    const float* __restrict__ x, float* __restrict__ out,
    float* __restrict__ feat, const float* __restrict__ w1,
    const float* __restrict__ w2, const float* __restrict__ w3,
    const float* __restrict__ pw1, unsigned short* __restrict__ w1f,
    unsigned short* __restrict__ w2f, unsigned short* __restrict__ w3f,
    float* __restrict__ pw1t) {
  const int blk = blockIdx.x;
  const int t = threadIdx.x;

  if (blk >= 792) {
    const int seg = blk - 792;
#pragma unroll
    for (int q = 0; q < 4; ++q) {
      int idx = seg * 1024 + q * 256 + t;  // 0..8191
      if (idx < 1024) {
        int nt = idx >> 9, lane_ = (idx >> 3) & 63, j = idx & 7;
        int lrow_ = lane_ & 15, lgrp_ = lane_ >> 4;
        int k = lgrp_ * 8 + j;
        w1f[idx] = f2bf(k < 27 ? w1[(nt * 16 + lrow_) * 27 + k] : 0.f);
      } else if (idx < 5632) {
        int id2 = idx - 1024;
        int tap = id2 >> 9, lane_ = (id2 >> 3) & 63, j = id2 & 7;
        int lrow_ = lane_ & 15, lgrp_ = lane_ >> 4;
        w2f[id2] = f2bf(w2[lrow_ * 288 + (lgrp_ * 8 + j) * 9 + tap]);
      } else if (idx < 8192) {
        int id3 = idx - 5632;
        int kk = id3 >> 9, lane_ = (id3 >> 3) & 63, j = id3 & 7;
        int lrow_ = lane_ & 15, lgrp_ = lane_ >> 4;
        int tap = 2 * kk + (lgrp_ >> 1);
        int c2 = (lgrp_ & 1) * 8 + j;
        float v = (lrow_ < 3 && tap < 9) ? w3[lrow_ * 144 + c2 * 9 + tap] : 0.f;
        w3f[id3] = f2bf(v);
      }
    }
    return;
  }

  if (blk >= 768) {
    // pw1 transpose: pw1[128][192] -> pw1t[192][128]; 24 tiles of 32x32
    const int tile = blk - 768;
    const int ko = (tile % 6) * 32;
    const int to = (tile / 6) * 32;
    __shared__ float tl[32][33];
    int ty = t >> 5, tx = t & 31;
#pragma unroll
    for (int r = 0; r < 4; ++r) {
      int row = r * 8 + ty;
      tl[row][tx] = pw1[(to + row) * 192 + ko + tx];
    }
    __syncthreads();
#pragma unroll
    for (int r = 0; r < 4; ++r) {
      int row = r * 8 + ty;
      pw1t[(ko + row) * 128 + to + tx] = tl[tx][row];
    }
    return;
  }

  // band block (b,c,i): copy 32x256 rows + full pool reduce in-block
  const int b = blk / 24;
  const int rem = blk - b * 24;
  const int c = rem >> 3;
  const int i = rem & 7;
  const int wv = t >> 6;
  const int lane = t & 63;
  const int j = lane >> 3;

  __shared__ float part[32];

  const size_t base4 = ((size_t)((b * 3 + c) * 256 + i * 32)) * 64;
  float s = 0.f;
#pragma unroll
  for (int k = 0; k < 8; ++k) {
    int r = k * 4 + wv;
    size_t F = base4 + (size_t)r * 64 + lane;
    float4 v = ((const float4*)x)[F];
    ((float4*)out)[F] = v;
    s += v.x + v.y + v.z + v.w;
  }
  s += __shfl_xor(s, 1, 64);
  s += __shfl_xor(s, 2, 64);
  s += __shfl_xor(s, 4, 64);
  if ((lane & 7) == 0) part[wv * 8 + j] = s;
  __syncthreads();
  if (t < 8) {
    float tot = part[t] + part[8 + t] + part[16 + t] + part[24 + t];
    feat[b * 192 + c * 64 + i * 8 + t] = tot * (1.f / 1024.f);
  }
}

// ================= K2: MLP -> posw (one block per batch image) ===============
__global__ __launch_bounds__(256) void mlp_kernel(
    const float* __restrict__ feat, const float* __restrict__ pw1t,
    const float* __restrict__ pb1, const float* __restrict__ pw2,
    const float* __restrict__ pb2, int* __restrict__ posw) {
  const int b = blockIdx.x;
  const int t = threadIdx.x;
  __shared__ float fs[192];
  __shared__ float part[2][128];
  __shared__ float hs[128];

  if (t < 192) fs[t] = feat[b * 192 + t];
  __syncthreads();

  {
    const int u = t & 127, h = t >> 7;
    float a0 = 0.f, a1 = 0.f;
    const float* wp = pw1t + (h * 96) * 128 + u;
    const float* fp = fs + h * 96;
#pragma unroll 12
    for (int k = 0; k < 96; k += 2) {
      a0 = fmaf(fp[k], wp[k * 128], a0);
      a1 = fmaf(fp[k + 1], wp[(k + 1) * 128], a1);
    }
    part[h][u] = a0 + a1;
  }
  __syncthreads();
  if (t < 128) hs[t] = fmaxf(part[0][t] + part[1][t] + pb1[t], 0.f);
  __syncthreads();

  const int wv = t >> 6, hl = (t >> 5) & 1, l = t & 31;
  const int jj = wv * 2 + hl;
  float a = 0.f;
#pragma unroll
  for (int q = 0; q < 4; ++q)
    a = fmaf(hs[q * 32 + l], pw2[jj * 128 + q * 32 + l], a);
#pragma unroll
  for (int m = 1; m <= 16; m <<= 1) a += __shfl_xor(a, m, 32);
  if (l == 0) {
    float a2 = a + pb2[jj];
    float sgm = 1.f / (1.f + expf(-a2));
    posw[b * 8 + jj] = (int)floorf(sgm * (float)(HH - PP));
  }
}

// ================= K3: MFMA patch pipeline (8-row blocks, 512 thr) ===========
// frames: out 8x32 @ (y0+rb, x0); h2 10x34 @ (-1,-1); h1/xcol 12x36 @ (-2,-2);
//         x 14x38 @ (-3,-3)
__global__ __launch_bounds__(512, 4) void patch_kernel(
    const float* __restrict__ x, float* __restrict__ out,
    const float* __restrict__ b1, const float* __restrict__ b2,
    const float* __restrict__ b3, const int* __restrict__ posw,
    const unsigned short* __restrict__ w1f, const unsigned short* __restrict__ w2f,
    const unsigned short* __restrict__ w3f) {
  const int blk = blockIdx.x;
  const int s = blk & 3;
  const int p = (blk >> 2) & 3;
  const int b = blk >> 4;
  const int rb = s * 8;
  const int t = threadIdx.x;
  const int wv = t >> 6;
  const int lane = t & 63;
  const int lrow = lane & 15;   // MFMA A-row / B-col / D-col
  const int lgrp = lane >> 4;   // MFMA k-group; D-row = lgrp*4+reg

  __shared__ __align__(16) float xs[3][532];              // 6384 B
  __shared__ __align__(16) unsigned short buf[432 * 40];  // 34560 B
  __shared__ __align__(16) unsigned short h2ls[352 * 16]; // 11264 B

  // positions first: stage addresses depend on them
  const int y0 = posw[b * 8 + p * 2 + 0];
  const int x0 = posw[b * 8 + p * 2 + 1];

  // ---- stage x window immediately (zero-padded f32)
#pragma unroll
  for (int k = 0; k < 4; ++k) {
    int idx = t + 512 * k;
    if (idx < 1596) {
      int c = idx / 532;
      int r = idx - c * 532;
      int ky = r / 38, kx = r - (r / 38) * 38;
      int gy = y0 + rb - 3 + ky, gx = x0 - 3 + kx;
      float v = 0.f;
      if ((unsigned)gy < 256u && (unsigned)gx < 256u)
        v = x[((size_t)(b * 3 + c) * 256 + gy) * 256 + gx];
      xs[c][r] = v;
    }
  }

  // fragment loads (overlap with stage latency)
  short8 b1f[2], b2f[9], b3f[5];
#pragma unroll
  for (int nt = 0; nt < 2; ++nt)
    b1f[nt] = *(const short8*)&w1f[(nt * 64 + lane) * 8];
#pragma unroll
  for (int tap = 0; tap < 9; ++tap)
    b2f[tap] = *(const short8*)&w2f[(tap * 64 + lane) * 8];
#pragma unroll
  for (int kk = 0; kk < 5; ++kk)
    b3f[kk] = *(const short8*)&w3f[(kk * 64 + lane) * 8];
  float b1v0 = b1[lrow], b1v1 = b1[16 + lrow];
  float bias2 = b2[lrow];
  float bias3 = (lrow < 3) ? b3[lrow] : 0.f;

  __syncthreads();

  // ---- im2col of xs -> buf (row=pos, k=c*9+dy*3+dx, 27 pad 32); 432 positions
  if (t < 432) {
    int pos = t;
    int jy = pos / 36, jx = pos - (pos / 36) * 36;
    unsigned short cv[32];
#pragma unroll
    for (int c = 0; c < 3; ++c)
#pragma unroll
      for (int dy = 0; dy < 3; ++dy)
#pragma unroll
        for (int dx = 0; dx < 3; ++dx)
          cv[c * 9 + dy * 3 + dx] = f2bf(xs[c][(jy + dy) * 38 + (jx + dx)]);
#pragma unroll
    for (int k = 27; k < 32; ++k) cv[k] = 0;
#pragma unroll
    for (int qq = 0; qq < 4; ++qq) {
      short8 v8;
#pragma unroll
      for (int j = 0; j < 8; ++j) v8[j] = (short)cv[qq * 8 + j];
      *(short8*)&buf[pos * 40 + qq * 8] = v8;
    }
  }
  __syncthreads();

  // ---- h1 GEMM  M=432 (27 tiles), N=32, K=32
  f32x4 acc1[4][2];
#pragma unroll
  for (int i = 0; i < 4; ++i) {
    int mt = wv + 8 * i;
    if (mt < 27) {
      short8 a = *(const short8*)&buf[(mt * 16 + lrow) * 40 + lgrp * 8];
      f32x4 z = f32x4{0.f, 0.f, 0.f, 0.f};
#pragma unroll
      for (int nt = 0; nt < 2; ++nt)
        acc1[i][nt] = __builtin_amdgcn_mfma_f32_16x16x32_bf16(a, b1f[nt], z, 0, 0, 0);
    }
  }
  __syncthreads();  // xcol reads done before overwriting buf with h1

  // epilogue: bias+relu+mask -> buf[pos][c1] bf16
#pragma unroll
  for (int i = 0; i < 4; ++i) {
    int mt = wv + 8 * i;
    if (mt < 27) {
#pragma unroll
      for (int r = 0; r < 4; ++r) {
        int pos = mt * 16 + lgrp * 4 + r;
        int jy = pos / 36, jx = pos - (pos / 36) * 36;
        bool inim = ((unsigned)(y0 + rb - 2 + jy) < 256u) &&
                    ((unsigned)(x0 - 2 + jx) < 256u);
#pragma unroll
        for (int nt = 0; nt < 2; ++nt) {
          float v = fmaxf(acc1[i][nt][r] + (nt ? b1v1 : b1v0), 0.f);
          buf[pos * 40 + nt * 16 + lrow] = inim ? f2bf(v) : (unsigned short)0;
        }
      }
    }
  }
  __syncthreads();

  // ---- h2 GEMM, M=352 (22 tiles, 340 valid), K = 9 taps x 32 c1
  f32x4 acc[3];
#pragma unroll
  for (int i = 0; i < 3; ++i) {
    int mt = wv + 8 * i;
    if (mt < 22) {
      int pos = mt * 16 + lrow;
      int posc = pos < 340 ? pos : 339;
      int iy = posc / 34, ix = posc - (posc / 34) * 34;
      const unsigned short* abase = &buf[(iy * 36 + ix) * 40 + lgrp * 8];
      f32x4 c = f32x4{0.f, 0.f, 0.f, 0.f};
#pragma unroll
      for (int dy = 0; dy < 3; ++dy)
#pragma unroll
        for (int dx = 0; dx < 3; ++dx) {
          short8 a = *(const short8*)(abase + (dy * 36 + dx) * 40);
          c = __builtin_amdgcn_mfma_f32_16x16x32_bf16(a, b2f[dy * 3 + dx], c, 0, 0, 0);
        }
      acc[i] = c;
    } else {
      acc[i] = f32x4{0.f, 0.f, 0.f, 0.f};
    }
  }
#pragma unroll
  for (int i = 0; i < 3; ++i) {
    int mt = wv + 8 * i;
    if (mt < 22) {
#pragma unroll
      for (int r = 0; r < 4; ++r) {
        int pos = mt * 16 + lgrp * 4 + r;
        if (pos < 340) {
          int iy = pos / 34, ix = pos - (pos / 34) * 34;
          bool inim = ((unsigned)(y0 + rb - 1 + iy) < 256u) &&
                      ((unsigned)(x0 - 1 + ix) < 256u);
          float v = fmaxf(acc[i][r] + bias2, 0.f);
          h2ls[pos * 16 + lrow] = inim ? f2bf(v) : (unsigned short)0;
        }
      }
    }
  }
  __syncthreads();

  // ---- h3 GEMM, M=256 (16 tiles), K=144 pad 160
  f32x4 acc3[2];
#pragma unroll
  for (int i = 0; i < 2; ++i) {
    int mt = wv * 2 + i;
    int pix = mt * 16 + lrow;
    int oy = pix >> 5, ox = pix & 31;
    f32x4 c = f32x4{0.f, 0.f, 0.f, 0.f};
#pragma unroll
    for (int kk = 0; kk < 5; ++kk) {
      int tap = 2 * kk + (lgrp >> 1);
      short8 a = short8{0, 0, 0, 0, 0, 0, 0, 0};
      if (tap < 9) {
        int dy = (tap * 11) >> 5;
        int dx = tap - dy * 3;
        a = *(const short8*)&h2ls[((oy + dy) * 34 + (ox + dx)) * 16 + (lgrp & 1) * 8];
      }
      c = __builtin_amdgcn_mfma_f32_16x16x32_bf16(a, b3f[kk], c, 0, 0, 0);
    }
    acc3[i] = c;
  }
  if (lrow < 3) {
#pragma unroll
    for (int i = 0; i < 2; ++i) {
      int mt = wv * 2 + i;
#pragma unroll
      for (int r = 0; r < 4; ++r) {
        int pix = mt * 16 + lgrp * 4 + r;
        int oy = pix >> 5, ox = pix & 31;
        float v = acc3[i][r] + bias3;
        float e = __expf(2.f * v);
        float val = (1.f - 2.f / (e + 1.f)) * 0.1f;
        atomicAdd(&out[((size_t)(b * 3 + lrow) * 256 + (y0 + rb + oy)) * 256 +
                       (x0 + ox)],
                  val);
      }
    }
  }
}

extern "C" void kernel_launch(void* const* d_in, const int* in_sizes, int n_in,
                              void* d_out, int out_size, void* d_ws, size_t ws_size,
                              hipStream_t stream) {
  const float* x   = (const float*)d_in[0];
  const float* w1  = (const float*)d_in[1];
  const float* b1  = (const float*)d_in[2];
  const float* w2  = (const float*)d_in[3];
  const float* b2  = (const float*)d_in[4];
  const float* w3  = (const float*)d_in[5];
  const float* b3  = (const float*)d_in[6];
  const float* pw1 = (const float*)d_in[7];
  const float* pb1 = (const float*)d_in[8];
  const float* pw2 = (const float*)d_in[9];
  const float* pb2 = (const float*)d_in[10];
  float* out = (float*)d_out;

  // ws layout (non-overlapping; ws proven >= 800 KB in round 5)
  float* feat = (float*)d_ws;                                    // bytes 0..24575
  unsigned short* w1f = (unsigned short*)((char*)d_ws + 24576);  // ..26623
  unsigned short* w2f = (unsigned short*)((char*)d_ws + 26624);  // ..35839
  unsigned short* w3f = (unsigned short*)((char*)d_ws + 35840);  // ..40959
  float* pw1t = (float*)((char*)d_ws + 40960);                   // ..139263
  int* posw = (int*)((char*)d_ws + 139264);                      // ..140287

  prep_kernel<<<800, 256, 0, stream>>>(x, out, feat, w1, w2, w3, pw1,
                                       w1f, w2f, w3f, pw1t);
  mlp_kernel<<<BATCH, 256, 0, stream>>>(feat, pw1t, pb1, pw2, pb2, posw);
  patch_kernel<<<BATCH * NPATCH * 4, 512, 0, stream>>>(
      x, out, b1, b2, b3, posw, w1f, w2f, w3f);
}